// Round 25
// baseline (419.289 us; speedup 1.0000x reference)
//
#include <hip/hip_runtime.h>

typedef _Float16 f16;
typedef _Float16 f16x8 __attribute__((ext_vector_type(8)));
typedef float    f32x4 __attribute__((ext_vector_type(4)));

#define BSZ 4
#define SL  2048
#define NK  24
#define DD  512
#define NPP 134   // p' in [0,133]
#define KI  8     // i's per chunk (xt chunk 67 MB -> L3-resident)

typedef const void GV __attribute__((address_space(1)));
typedef void       LV __attribute__((address_space(3)));

__device__ __forceinline__ void gload_lds16(const void* gp, void* lp) {
  // dest = lp (wave-uniform) + lane*16
  __builtin_amdgcn_global_load_lds((GV*)gp, (LV*)lp, 16, 0, 0);
}

// ---------------- prep: A-fragment table
// afrag[i][p'][lane][j] = val(2047 - 16*(p'-6) - (lane&15) + 8*(lane>>4) + j)
// val(x) = (0<=x<2048) ? v[2047-x, i] * lam_i^0.25 : 0
__global__ void k_afrag(const float* __restrict__ eig_vals,
                        const float* __restrict__ eig_vecs,
                        f16* __restrict__ afrag) {
  int i = blockIdx.x, pp = blockIdx.y;
  int l = threadIdx.x;  // 64
  float sc = sqrtf(sqrtf(eig_vals[i]));
  int base = 2047 - 16 * (pp - 6) - (l & 15) + 8 * (l >> 4);
  f16 tmp[8];
#pragma unroll
  for (int j = 0; j < 8; ++j) {
    int x = base + j;
    float v = (x >= 0 && x < SL) ? eig_vecs[(size_t)(SL - 1 - x) * NK + i] * sc : 0.f;
    tmp[j] = (f16)v;
  }
  *(f16x8*)(afrag + (((size_t)i * NPP + pp) * 64 + l) * 8) = *(const f16x8*)tmp;
}

// ---------------- prep: ut[b][d][s] = (f16) u[b][s][d]
__global__ void k_tu(const float* __restrict__ u, f16* __restrict__ ut) {
  __shared__ float tile[32][33];
  int b = blockIdx.z;
  int s0 = blockIdx.x * 32, d0 = blockIdx.y * 32;
  int tx = threadIdx.x, ty = threadIdx.y;
#pragma unroll
  for (int r = 0; r < 4; ++r) {
    int s = s0 + ty * 4 + r;
    tile[ty * 4 + r][tx] = u[((size_t)b * SL + s) * DD + d0 + tx];
  }
  __syncthreads();
#pragma unroll
  for (int r = 0; r < 4; ++r) {
    int d = d0 + ty * 4 + r;
    ut[((size_t)b * DD + d) * SL + s0 + tx] = (f16)tile[tx][ty * 4 + r];
  }
}

// ---------------- prep: mht[e][k] = (f16) m_phi[k][e]   (B^T layout)
__global__ void k_tm(const float* __restrict__ mp, f16* __restrict__ mht) {
  __shared__ float tile[32][33];
  int k0 = blockIdx.x * 32, e0 = blockIdx.y * 32;
  int tx = threadIdx.x, ty = threadIdx.y;
#pragma unroll
  for (int r = 0; r < 4; ++r)
    tile[ty * 4 + r][tx] = mp[(size_t)(k0 + ty * 4 + r) * DD + e0 + tx];
  __syncthreads();
#pragma unroll
  for (int r = 0; r < 4; ++r)
    mht[(size_t)(e0 + ty * 4 + r) * (NK * DD) + k0 + tx] = (f16)tile[tx][ty * 4 + r];
}

// ---------------- phase A: causal Toeplitz conv -> xt[b][t][iL*512+d] (fp16, chunk-local)
// R24 structure with the VGPR fix: __launch_bounds__(128, 4) caps VGPR at 128
// (demand ~120, R23-proven) -> VGPR no longer binding; LDS (24 KB) caps residency
// at 6 blocks/CU = 12 waves = 3 waves/SIMD (R24's unconstrained build relaxed to
// 172 VGPR -> only 2 waves/SIMD -> regression). Spill tripwire: VGPR==128 AND
// WRITE >> 65MB => revert to R23.
// Barrier-free, wave-private 64-row stripes, counted vmcnt(6), B reg ping-pong,
// XCD-pinned (dq,b) via lin&7, anti-symmetric tb (per-CU nIter sum = 272 always).
__global__ __launch_bounds__(128, 4) void k_conv(
    const f16* __restrict__ ut, const f16* __restrict__ afrag,
    f16* __restrict__ xt, int ibase) {
  __shared__ f16 bt[3][128 * 32];   // 24 KB
  const int tid = threadIdx.x;
  const int lin = blockIdx.x + (blockIdx.y << 6) + (blockIdx.z << 9);
  const int dq = lin & 3;
  const int b  = (lin >> 2) & 3;
  const int q  = (lin >> 4) & 3;
  const int iL = (lin >> 6) & 7;
  const int r  = (lin >> 9) & 3;
  const int tb = (r == 0) ? q : (r == 1) ? (q + 4) : (r == 2) ? (11 - q) : (15 - q);
  const int iG = ibase + iL;
  const int t0 = tb * 128;

  const int w = tid >> 6, l = tid & 63;   // w in {0,1}
  const int l15 = l & 15, lq = l >> 4;
  // staging/read swizzle pair (R4-proven, conflicts = 0)
  const int stage_col = ((l & 3) ^ ((l >> 3) & 3)) * 8;
  const int stage_row = l >> 2;
  const int rd_x = (lq ^ ((l15 >> 1) & 3)) * 16;

  const f16* utb = ut + (size_t)b * DD * SL;
  const f16* afi = afrag + ((size_t)iG * NPP * 64 + l) * 8;

  auto stage = [&](int buf, int s0) {
#pragma unroll
    for (int j = 0; j < 4; ++j) {
      int row = w * 64 + j * 16 + stage_row;
      gload_lds16(utb + (size_t)(dq * 128 + row) * SL + s0 + stage_col,
                  &bt[buf][(w * 64 + j * 16) * 32]);
    }
  };

  f32x4 acc[8][4];
#pragma unroll
  for (int m = 0; m < 8; ++m)
#pragma unroll
    for (int n = 0; n < 4; ++n) acc[m][n] = (f32x4){0.f, 0.f, 0.f, 0.f};

  const int nIter = 4 * (tb + 1);   // >= 4, even
  int pp0 = 8 * tb + 6;

  // prologue: stage0, full A window (8), stage1; vmcnt(4) drains stage0 + A window
  stage(0, 0);
  f16x8 A[8];
#pragma unroll
  for (int m = 0; m < 8; ++m)
    A[m] = *(const f16x8*)(afi + (size_t)(pp0 + m) * 512);
  stage(1, 32);
  asm volatile("s_waitcnt vmcnt(4)" ::: "memory");
  __builtin_amdgcn_sched_barrier(0);

  // current B frags (iter 0) from bt[0]
  f16x8 Bc[4], Bn[4];
#pragma unroll
  for (int n = 0; n < 4; ++n) {
    int row = w * 64 + n * 16 + l15;
    Bc[n] = *(const f16x8*)((const char*)&bt[0][0] + row * 64 + rd_x);
  }

  int ra = 0;   // buffer index of iter `it`
  for (int it = 0; it < nIter; it += 2) {
    const bool notlast = (it + 2 < nIter);
    // ---- body a (iter it): MFMA A[0..7] x Bc; read Bn (iter it+1) after drain
    int ppn = pp0 - 2; if (ppn < 0) ppn = 0;   // tail clamp (values unused)
    const f16* fpt = afi + (size_t)ppn * 512;
    f16x8 f0 = *(const f16x8*)fpt;
    f16x8 f1 = *(const f16x8*)(fpt + 512);
    int sa = ra + 2; if (sa >= 3) sa -= 3;
    int rb = ra + 1; if (rb >= 3) rb -= 3;
    if (notlast) {
      stage(sa, (it + 2) * 32);
      asm volatile("s_waitcnt vmcnt(6)" ::: "memory");   // drains {g,g,stage(it+1)}
    } else {
      asm volatile("s_waitcnt vmcnt(2)" ::: "memory");   // exact tail drain
    }
    __builtin_amdgcn_sched_barrier(0);
#pragma unroll
    for (int n = 0; n < 4; ++n) {
      int row = w * 64 + n * 16 + l15;
      Bn[n] = *(const f16x8*)((const char*)&bt[rb][0] + row * 64 + rd_x);
    }

    __builtin_amdgcn_s_setprio(1);
#pragma unroll
    for (int m = 0; m < 8; ++m)
#pragma unroll
      for (int n = 0; n < 4; ++n)
        acc[m][n] = __builtin_amdgcn_mfma_f32_16x16x32_f16(A[m], Bc[n], acc[m][n], 0, 0, 0);
    __builtin_amdgcn_s_setprio(0);

    // ---- body b (iter it+1): MFMA {f0,f1,A[0..5]} x Bn; read Bc (iter it+2) after drain
    int pp2 = pp0 - 4; if (pp2 < 0) pp2 = 0;
    const f16* gpt = afi + (size_t)pp2 * 512;
    f16x8 g0 = *(const f16x8*)gpt;
    f16x8 g1 = *(const f16x8*)(gpt + 512);
    if (it + 3 < nIter) stage(ra, (it + 3) * 32);
    if (notlast) {
      asm volatile("s_waitcnt vmcnt(6)" ::: "memory");   // drains {f,f,stage(it+2)}
    } else {
      asm volatile("s_waitcnt vmcnt(2)" ::: "memory");   // drains f0,f1
    }
    __builtin_amdgcn_sched_barrier(0);
    if (notlast) {
#pragma unroll
      for (int n = 0; n < 4; ++n) {
        int row = w * 64 + n * 16 + l15;
        Bc[n] = *(const f16x8*)((const char*)&bt[sa][0] + row * 64 + rd_x);
      }
    }

    __builtin_amdgcn_s_setprio(1);
#pragma unroll
    for (int n = 0; n < 4; ++n) {
      acc[0][n] = __builtin_amdgcn_mfma_f32_16x16x32_f16(f0, Bn[n], acc[0][n], 0, 0, 0);
      acc[1][n] = __builtin_amdgcn_mfma_f32_16x16x32_f16(f1, Bn[n], acc[1][n], 0, 0, 0);
#pragma unroll
      for (int m = 2; m < 8; ++m)
        acc[m][n] = __builtin_amdgcn_mfma_f32_16x16x32_f16(A[m - 2], Bn[n], acc[m][n], 0, 0, 0);
    }
    __builtin_amdgcn_s_setprio(0);

    // rotate window by 4 (16 movs per 2 iters)
    A[7] = A[3]; A[6] = A[2]; A[5] = A[1]; A[4] = A[0];
    A[3] = f1;   A[2] = f0;   A[1] = g1;   A[0] = g0;
    pp0 -= 4;
    ra = sa;
  }

  // store xt fp16 (regular stores: keep chunk L3-hot for the following gemm)
  const size_t rowlen = (size_t)KI * DD;
  const int dbase = dq * 128 + w * 64;
#pragma unroll
  for (int m = 0; m < 8; ++m) {
    int t = t0 + m * 16 + lq * 4;
#pragma unroll
    for (int n = 0; n < 4; ++n) {
      int d = dbase + n * 16 + l15;
      f16* dst = xt + ((size_t)(b * SL + t) * KI + iL) * DD + d;
#pragma unroll
      for (int r2 = 0; r2 < 4; ++r2)
        dst[(size_t)r2 * rowlen] = (f16)acc[m][n][r2];
    }
  }
}

// ---------------- phase B: out[8192][512] (+)= xt[8192][4096] @ mht[:, kc0:+4096]^T
// R22 gemm verbatim (XCD-swizzled R10 schedule — only config with small FETCH).
__global__ __launch_bounds__(256, 2) void k_gemm(
    const f16* __restrict__ xt, const f16* __restrict__ mht,
    float* __restrict__ out, int kc0, int beta) {
  __shared__ f16 at[3][64 * 64];      // 24 KB
  __shared__ f16 btl[3][128 * 64];    // 48 KB
  const int AK = KI * DD;             // 4096
  const int tid = threadIdx.x;
  const int orig = blockIdx.x + (blockIdx.y << 2);   // 0..511
  const int swz  = (orig & 7) * 64 + (orig >> 3);    // bijective XCD swizzle
  const int n0 = (swz & 3) * 128;
  const int m0 = (swz >> 2) * 64;
  const int w = tid >> 6, l = tid & 63;
  const int l15 = l & 15, lq = l >> 4;
  const int wm = w >> 1, wn = w & 1;
  const int stage_col = ((l & 7) ^ (l >> 3)) * 8;
  const int stage_row = l >> 3;

  auto stage = [&](int buf, int k0) {
#pragma unroll
    for (int j = 0; j < 2; ++j) {  // A tile [64][64]
      int row = (w * 2 + j) * 8 + stage_row;
      gload_lds16(xt + (size_t)(m0 + row) * AK + k0 + stage_col,
                  &at[buf][(w * 2 + j) * 8 * 64]);
    }
#pragma unroll
    for (int j = 0; j < 4; ++j) {  // B tile [128][64]
      int row = (w * 4 + j) * 8 + stage_row;
      gload_lds16(mht + (size_t)(n0 + row) * (NK * DD) + kc0 + k0 + stage_col,
                  &btl[buf][(w * 4 + j) * 8 * 64]);
    }
  };

  f32x4 acc[2][4];
#pragma unroll
  for (int m = 0; m < 2; ++m)
#pragma unroll
    for (int n = 0; n < 4; ++n) acc[m][n] = (f32x4){0.f, 0.f, 0.f, 0.f};

  const int nIter = AK / 64;   // 64
  stage(0, 0);
  stage(1, 64);
  asm volatile("s_waitcnt vmcnt(6)" ::: "memory");
  __builtin_amdgcn_s_barrier();
  __builtin_amdgcn_sched_barrier(0);

  for (int it = 0; it < nIter; ++it) {
    const int bufR = it % 3;
    f16x8 Af[2][2], Bf[2][4];
#pragma unroll
    for (int ks = 0; ks < 2; ++ks) {
#pragma unroll
      for (int m = 0; m < 2; ++m) {
        int lin2 = (wm * 32 + m * 16 + l15) * 128 + ks * 64 + lq * 16;
        lin2 ^= (l15 & 7) << 4;
        Af[ks][m] = *(const f16x8*)((const char*)&at[bufR][0] + lin2);
      }
#pragma unroll
      for (int n = 0; n < 4; ++n) {
        int lin2 = (wn * 64 + n * 16 + l15) * 128 + ks * 64 + lq * 16;
        lin2 ^= (l15 & 7) << 4;
        Bf[ks][n] = *(const f16x8*)((const char*)&btl[bufR][0] + lin2);
      }
    }

    if (it + 2 < nIter) stage((it + 2) % 3, (it + 2) * 64);

    asm volatile("s_waitcnt vmcnt(6)" ::: "memory");
    __builtin_amdgcn_s_barrier();
    __builtin_amdgcn_sched_barrier(0);

    __builtin_amdgcn_s_setprio(1);
#pragma unroll
    for (int ks = 0; ks < 2; ++ks)
#pragma unroll
      for (int m = 0; m < 2; ++m)
#pragma unroll
        for (int n = 0; n < 4; ++n)
          acc[m][n] = __builtin_amdgcn_mfma_f32_16x16x32_f16(
              Af[ks][m], Bf[ks][n], acc[m][n], 0, 0, 0);
    __builtin_amdgcn_s_setprio(0);
  }

#pragma unroll
  for (int m = 0; m < 2; ++m) {
    int row = m0 + wm * 32 + m * 16 + lq * 4;
#pragma unroll
    for (int n = 0; n < 4; ++n) {
      int e = n0 + wn * 64 + n * 16 + l15;
      float* dst = out + (size_t)row * DD + e;
#pragma unroll
      for (int r = 0; r < 4; ++r) {
        float v = acc[m][n][r];
        if (beta) v += dst[(size_t)r * DD];
        dst[(size_t)r * DD] = v;
      }
    }
  }
}

extern "C" void kernel_launch(void* const* d_in, const int* in_sizes, int n_in,
                              void* d_out, int out_size, void* d_ws, size_t ws_size,
                              hipStream_t stream) {
  const float* u    = (const float*)d_in[0];  // [4,2048,512]
  const float* ev   = (const float*)d_in[1];  // [24]
  const float* evec = (const float*)d_in[2];  // [2048,24]
  const float* mp   = (const float*)d_in[3];  // [12288,512]
  float* out = (float*)d_out;
  char* ws = (char*)d_ws;

  const size_t UT_OFF  = 0;                        // 8,388,608 B
  const size_t MHT_OFF = 8388608;                  // 12,582,912 B
  const size_t AF_OFF  = 20971520;                 // 24*134*64*8*2 = 3,293,184 B
  const size_t XT_OFF  = 24264704;                 // + 8*8,388,608 = 91.4 MB total

  f16* ut    = (f16*)(ws + UT_OFF);
  f16* mht   = (f16*)(ws + MHT_OFF);
  f16* afrag = (f16*)(ws + AF_OFF);
  f16* xt    = (f16*)(ws + XT_OFF);

  k_afrag<<<dim3(24, NPP), 64, 0, stream>>>(ev, evec, afrag);
  k_tu<<<dim3(SL / 32, DD / 32, BSZ), dim3(32, 8), 0, stream>>>(u, ut);
  k_tm<<<dim3((NK * DD) / 32, DD / 32), dim3(32, 8), 0, stream>>>(mp, mht);

  for (int c = 0; c < NK / KI; ++c) {
    k_conv<<<dim3(64, KI, BSZ), 128, 0, stream>>>(ut, afrag, xt, c * KI);
    k_gemm<<<dim3(DD / 128, (BSZ * SL) / 64), 256, 0, stream>>>(
        xt, mht, out, c * KI * DD, c > 0);
  }
}

// Round 26
// 354.465 us; speedup vs baseline: 1.1829x; 1.1829x over previous
//
#include <hip/hip_runtime.h>

typedef _Float16 f16;
typedef _Float16 f16x8 __attribute__((ext_vector_type(8)));
typedef float    f32x4 __attribute__((ext_vector_type(4)));

#define BSZ 4
#define SL  2048
#define NK  24
#define DD  512
#define NPP 134   // p' in [0,133]
#define KI  8     // i's per chunk (xt chunk 67 MB -> L3-resident)

typedef const void GV __attribute__((address_space(1)));
typedef void       LV __attribute__((address_space(3)));

__device__ __forceinline__ void gload_lds16(const void* gp, void* lp) {
  // dest = lp (wave-uniform) + lane*16
  __builtin_amdgcn_global_load_lds((GV*)gp, (LV*)lp, 16, 0, 0);
}

// ---------------- prep: A-fragment table
// afrag[i][p'][lane][j] = val(2047 - 16*(p'-6) - (lane&15) + 8*(lane>>4) + j)
// val(x) = (0<=x<2048) ? v[2047-x, i] * lam_i^0.25 : 0
__global__ void k_afrag(const float* __restrict__ eig_vals,
                        const float* __restrict__ eig_vecs,
                        f16* __restrict__ afrag) {
  int i = blockIdx.x, pp = blockIdx.y;
  int l = threadIdx.x;  // 64
  float sc = sqrtf(sqrtf(eig_vals[i]));
  int base = 2047 - 16 * (pp - 6) - (l & 15) + 8 * (l >> 4);
  f16 tmp[8];
#pragma unroll
  for (int j = 0; j < 8; ++j) {
    int x = base + j;
    float v = (x >= 0 && x < SL) ? eig_vecs[(size_t)(SL - 1 - x) * NK + i] * sc : 0.f;
    tmp[j] = (f16)v;
  }
  *(f16x8*)(afrag + (((size_t)i * NPP + pp) * 64 + l) * 8) = *(const f16x8*)tmp;
}

// ---------------- prep: ut[b][d][s] = (f16) u[b][s][d]
__global__ void k_tu(const float* __restrict__ u, f16* __restrict__ ut) {
  __shared__ float tile[32][33];
  int b = blockIdx.z;
  int s0 = blockIdx.x * 32, d0 = blockIdx.y * 32;
  int tx = threadIdx.x, ty = threadIdx.y;
#pragma unroll
  for (int r = 0; r < 4; ++r) {
    int s = s0 + ty * 4 + r;
    tile[ty * 4 + r][tx] = u[((size_t)b * SL + s) * DD + d0 + tx];
  }
  __syncthreads();
#pragma unroll
  for (int r = 0; r < 4; ++r) {
    int d = d0 + ty * 4 + r;
    ut[((size_t)b * DD + d) * SL + s0 + tx] = (f16)tile[tx][ty * 4 + r];
  }
}

// ---------------- prep: mht[e][k] = (f16) m_phi[k][e]   (B^T layout)
__global__ void k_tm(const float* __restrict__ mp, f16* __restrict__ mht) {
  __shared__ float tile[32][33];
  int k0 = blockIdx.x * 32, e0 = blockIdx.y * 32;
  int tx = threadIdx.x, ty = threadIdx.y;
#pragma unroll
  for (int r = 0; r < 4; ++r)
    tile[ty * 4 + r][tx] = mp[(size_t)(k0 + ty * 4 + r) * DD + e0 + tx];
  __syncthreads();
#pragma unroll
  for (int r = 0; r < 4; ++r)
    mht[(size_t)(e0 + ty * 4 + r) * (NK * DD) + k0 + tx] = (f16)tile[tx][ty * 4 + r];
}

// ---------------- phase A: causal Toeplitz conv -> xt[b][t][iL*512+d] (fp16, chunk-local)
// R23 structure (barrier-free, wave-private 64-row stripes, XCD-pinned (dh,b),
// anti-symmetric balanced tb, counted vmcnt(6), A reg window, B reg ping-pong)
// with LDS cut 48->32 KB: with B ping-pong, buffer for iter `it` is dead once its
// frags are in Bc/Bn regs (one body before stage(it+2) reuses it; per-wave program
// order makes the WAR safe) -> 2 buffers suffice. VGPR 120 allows 4 waves/SIMD;
// LDS 32KB allows 5 blocks -> residency 4 blocks/CU = 16 waves (was 12).
// launch_bounds stays (256,2): min-arg>=3 pins VGPR=84+spill (R12/R19); no-bound
// or (128,4) relaxes/ignores to 172 (R24/R25).
__global__ __launch_bounds__(256, 2) void k_conv(
    const f16* __restrict__ ut, const f16* __restrict__ afrag,
    f16* __restrict__ xt, int ibase) {
  __shared__ f16 bt[2][256 * 32];   // 32 KB
  const int tid = threadIdx.x;
  const int lin = blockIdx.x + (blockIdx.y << 5) + (blockIdx.z << 8);
  const int dh = lin & 1;           // lin%8 == XCD id pins (dh,b): 1MB ut-half/XCD-L2
  const int b  = (lin >> 1) & 3;
  const int iL = (lin >> 3) & 7;
  const int q  = (lin >> 6) & 3;
  const int r  = (lin >> 8) & 3;
  const int tb = (r == 0) ? q : (r == 1) ? (q + 4) : (r == 2) ? (11 - q) : (15 - q);
  const int iG = ibase + iL;
  const int t0 = tb * 128;

  const int w = tid >> 6, l = tid & 63;
  const int l15 = l & 15, lq = l >> 4;
  // staging/read swizzle pair (R4-proven, conflicts = 0)
  const int stage_col = ((l & 3) ^ ((l >> 3) & 3)) * 8;
  const int stage_row = l >> 2;
  const int rd_x = (lq ^ ((l15 >> 1) & 3)) * 16;

  const f16* utb = ut + (size_t)b * DD * SL;
  const f16* afi = afrag + ((size_t)iG * NPP * 64 + l) * 8;

  auto stage = [&](int buf, int s0) {
#pragma unroll
    for (int j = 0; j < 4; ++j) {
      int row = w * 64 + j * 16 + stage_row;
      gload_lds16(utb + (size_t)(dh * 256 + row) * SL + s0 + stage_col,
                  &bt[buf][(w * 64 + j * 16) * 32]);
    }
  };

  f32x4 acc[8][4];
#pragma unroll
  for (int m = 0; m < 8; ++m)
#pragma unroll
    for (int n = 0; n < 4; ++n) acc[m][n] = (f32x4){0.f, 0.f, 0.f, 0.f};

  const int nIter = 4 * (tb + 1);   // >= 4, even
  int pp0 = 8 * tb + 6;

  // prologue: stage0, full A window (8), stage1; vmcnt(4) drains stage0 + A window
  stage(0, 0);
  f16x8 A[8];
#pragma unroll
  for (int m = 0; m < 8; ++m)
    A[m] = *(const f16x8*)(afi + (size_t)(pp0 + m) * 512);
  stage(1, 32);
  asm volatile("s_waitcnt vmcnt(4)" ::: "memory");
  __builtin_amdgcn_sched_barrier(0);

  // current B frags (iter 0) from bt[0]
  f16x8 Bc[4], Bn[4];
#pragma unroll
  for (int n = 0; n < 4; ++n) {
    int row = w * 64 + n * 16 + l15;
    Bc[n] = *(const f16x8*)((const char*)&bt[0][0] + row * 64 + rd_x);
  }

  for (int it = 0; it < nIter; it += 2) {
    const bool notlast = (it + 2 < nIter);
    const int pa = it & 1;        // == 0: buffer of iter it (even)
    // ---- body a (iter it): MFMA A[0..7] x Bc; read Bn (iter it+1) after drain
    int ppn = pp0 - 2; if (ppn < 0) ppn = 0;   // tail clamp (values unused)
    const f16* fpt = afi + (size_t)ppn * 512;
    f16x8 f0 = *(const f16x8*)fpt;
    f16x8 f1 = *(const f16x8*)(fpt + 512);
    if (notlast) {
      stage(0, (it + 2) * 32);    // buf (it+2)%2 == 0; its iter-it frags already in Bc
      asm volatile("s_waitcnt vmcnt(6)" ::: "memory");   // drains {g,g,stage(it+1)}
    } else {
      asm volatile("s_waitcnt vmcnt(2)" ::: "memory");   // exact tail drain
    }
    __builtin_amdgcn_sched_barrier(0);
#pragma unroll
    for (int n = 0; n < 4; ++n) {
      int row = w * 64 + n * 16 + l15;
      Bn[n] = *(const f16x8*)((const char*)&bt[1][0] + row * 64 + rd_x);
    }

    __builtin_amdgcn_s_setprio(1);
#pragma unroll
    for (int m = 0; m < 8; ++m)
#pragma unroll
      for (int n = 0; n < 4; ++n)
        acc[m][n] = __builtin_amdgcn_mfma_f32_16x16x32_f16(A[m], Bc[n], acc[m][n], 0, 0, 0);
    __builtin_amdgcn_s_setprio(0);

    // ---- body b (iter it+1): MFMA {f0,f1,A[0..5]} x Bn; read Bc (iter it+2) after drain
    int pp2 = pp0 - 4; if (pp2 < 0) pp2 = 0;
    const f16* gpt = afi + (size_t)pp2 * 512;
    f16x8 g0 = *(const f16x8*)gpt;
    f16x8 g1 = *(const f16x8*)(gpt + 512);
    if (it + 3 < nIter) stage(1, (it + 3) * 32);   // buf (it+3)%2 == 1; iter it+1 frags in Bn
    if (notlast) {
      asm volatile("s_waitcnt vmcnt(6)" ::: "memory");   // drains {f,f,stage(it+2)}
    } else {
      asm volatile("s_waitcnt vmcnt(2)" ::: "memory");   // drains f0,f1
    }
    __builtin_amdgcn_sched_barrier(0);
    if (notlast) {
#pragma unroll
      for (int n = 0; n < 4; ++n) {
        int row = w * 64 + n * 16 + l15;
        Bc[n] = *(const f16x8*)((const char*)&bt[0][0] + row * 64 + rd_x);
      }
    }
    (void)pa;

    __builtin_amdgcn_s_setprio(1);
#pragma unroll
    for (int n = 0; n < 4; ++n) {
      acc[0][n] = __builtin_amdgcn_mfma_f32_16x16x32_f16(f0, Bn[n], acc[0][n], 0, 0, 0);
      acc[1][n] = __builtin_amdgcn_mfma_f32_16x16x32_f16(f1, Bn[n], acc[1][n], 0, 0, 0);
#pragma unroll
      for (int m = 2; m < 8; ++m)
        acc[m][n] = __builtin_amdgcn_mfma_f32_16x16x32_f16(A[m - 2], Bn[n], acc[m][n], 0, 0, 0);
    }
    __builtin_amdgcn_s_setprio(0);

    // rotate window by 4 (16 movs per 2 iters)
    A[7] = A[3]; A[6] = A[2]; A[5] = A[1]; A[4] = A[0];
    A[3] = f1;   A[2] = f0;   A[1] = g1;   A[0] = g0;
    pp0 -= 4;
  }

  // store xt fp16 (regular stores: keep chunk L3-hot for the following gemm)
  const size_t rowlen = (size_t)KI * DD;
  const int dbase = dh * 256 + w * 64;
#pragma unroll
  for (int m = 0; m < 8; ++m) {
    int t = t0 + m * 16 + lq * 4;
#pragma unroll
    for (int n = 0; n < 4; ++n) {
      int d = dbase + n * 16 + l15;
      f16* dst = xt + ((size_t)(b * SL + t) * KI + iL) * DD + d;
#pragma unroll
      for (int r2 = 0; r2 < 4; ++r2)
        dst[(size_t)r2 * rowlen] = (f16)acc[m][n][r2];
    }
  }
}

// ---------------- phase B: out[8192][512] (+)= xt[8192][4096] @ mht[:, kc0:+4096]^T
// R22 gemm verbatim (XCD-swizzled R10 schedule — only config with small FETCH).
__global__ __launch_bounds__(256, 2) void k_gemm(
    const f16* __restrict__ xt, const f16* __restrict__ mht,
    float* __restrict__ out, int kc0, int beta) {
  __shared__ f16 at[3][64 * 64];      // 24 KB
  __shared__ f16 btl[3][128 * 64];    // 48 KB
  const int AK = KI * DD;             // 4096
  const int tid = threadIdx.x;
  const int orig = blockIdx.x + (blockIdx.y << 2);   // 0..511
  const int swz  = (orig & 7) * 64 + (orig >> 3);    // bijective XCD swizzle
  const int n0 = (swz & 3) * 128;
  const int m0 = (swz >> 2) * 64;
  const int w = tid >> 6, l = tid & 63;
  const int l15 = l & 15, lq = l >> 4;
  const int wm = w >> 1, wn = w & 1;
  const int stage_col = ((l & 7) ^ (l >> 3)) * 8;
  const int stage_row = l >> 3;

  auto stage = [&](int buf, int k0) {
#pragma unroll
    for (int j = 0; j < 2; ++j) {  // A tile [64][64]
      int row = (w * 2 + j) * 8 + stage_row;
      gload_lds16(xt + (size_t)(m0 + row) * AK + k0 + stage_col,
                  &at[buf][(w * 2 + j) * 8 * 64]);
    }
#pragma unroll
    for (int j = 0; j < 4; ++j) {  // B tile [128][64]
      int row = (w * 4 + j) * 8 + stage_row;
      gload_lds16(mht + (size_t)(n0 + row) * (NK * DD) + kc0 + k0 + stage_col,
                  &btl[buf][(w * 4 + j) * 8 * 64]);
    }
  };

  f32x4 acc[2][4];
#pragma unroll
  for (int m = 0; m < 2; ++m)
#pragma unroll
    for (int n = 0; n < 4; ++n) acc[m][n] = (f32x4){0.f, 0.f, 0.f, 0.f};

  const int nIter = AK / 64;   // 64
  stage(0, 0);
  stage(1, 64);
  asm volatile("s_waitcnt vmcnt(6)" ::: "memory");
  __builtin_amdgcn_s_barrier();
  __builtin_amdgcn_sched_barrier(0);

  for (int it = 0; it < nIter; ++it) {
    const int bufR = it % 3;
    f16x8 Af[2][2], Bf[2][4];
#pragma unroll
    for (int ks = 0; ks < 2; ++ks) {
#pragma unroll
      for (int m = 0; m < 2; ++m) {
        int lin2 = (wm * 32 + m * 16 + l15) * 128 + ks * 64 + lq * 16;
        lin2 ^= (l15 & 7) << 4;
        Af[ks][m] = *(const f16x8*)((const char*)&at[bufR][0] + lin2);
      }
#pragma unroll
      for (int n = 0; n < 4; ++n) {
        int lin2 = (wn * 64 + n * 16 + l15) * 128 + ks * 64 + lq * 16;
        lin2 ^= (l15 & 7) << 4;
        Bf[ks][n] = *(const f16x8*)((const char*)&btl[bufR][0] + lin2);
      }
    }

    if (it + 2 < nIter) stage((it + 2) % 3, (it + 2) * 64);

    asm volatile("s_waitcnt vmcnt(6)" ::: "memory");
    __builtin_amdgcn_s_barrier();
    __builtin_amdgcn_sched_barrier(0);

    __builtin_amdgcn_s_setprio(1);
#pragma unroll
    for (int ks = 0; ks < 2; ++ks)
#pragma unroll
      for (int m = 0; m < 2; ++m)
#pragma unroll
        for (int n = 0; n < 4; ++n)
          acc[m][n] = __builtin_amdgcn_mfma_f32_16x16x32_f16(
              Af[ks][m], Bf[ks][n], acc[m][n], 0, 0, 0);
    __builtin_amdgcn_s_setprio(0);
  }

#pragma unroll
  for (int m = 0; m < 2; ++m) {
    int row = m0 + wm * 32 + m * 16 + lq * 4;
#pragma unroll
    for (int n = 0; n < 4; ++n) {
      int e = n0 + wn * 64 + n * 16 + l15;
      float* dst = out + (size_t)row * DD + e;
#pragma unroll
      for (int r = 0; r < 4; ++r) {
        float v = acc[m][n][r];
        if (beta) v += dst[(size_t)r * DD];
        dst[(size_t)r * DD] = v;
      }
    }
  }
}

extern "C" void kernel_launch(void* const* d_in, const int* in_sizes, int n_in,
                              void* d_out, int out_size, void* d_ws, size_t ws_size,
                              hipStream_t stream) {
  const float* u    = (const float*)d_in[0];  // [4,2048,512]
  const float* ev   = (const float*)d_in[1];  // [24]
  const float* evec = (const float*)d_in[2];  // [2048,24]
  const float* mp   = (const float*)d_in[3];  // [12288,512]
  float* out = (float*)d_out;
  char* ws = (char*)d_ws;

  const size_t UT_OFF  = 0;                        // 8,388,608 B
  const size_t MHT_OFF = 8388608;                  // 12,582,912 B
  const size_t AF_OFF  = 20971520;                 // 24*134*64*8*2 = 3,293,184 B
  const size_t XT_OFF  = 24264704;                 // + 8*8,388,608 = 91.4 MB total

  f16* ut    = (f16*)(ws + UT_OFF);
  f16* mht   = (f16*)(ws + MHT_OFF);
  f16* afrag = (f16*)(ws + AF_OFF);
  f16* xt    = (f16*)(ws + XT_OFF);

  k_afrag<<<dim3(24, NPP), 64, 0, stream>>>(ev, evec, afrag);
  k_tu<<<dim3(SL / 32, DD / 32, BSZ), dim3(32, 8), 0, stream>>>(u, ut);
  k_tm<<<dim3((NK * DD) / 32, DD / 32), dim3(32, 8), 0, stream>>>(mp, mht);

  for (int c = 0; c < NK / KI; ++c) {
    k_conv<<<dim3(32, KI, BSZ), 256, 0, stream>>>(ut, afrag, xt, c * KI);
    k_gemm<<<dim3(DD / 128, (BSZ * SL) / 64), 256, 0, stream>>>(
        xt, mht, out, c * KI * DD, c > 0);
  }
}